// Round 1
// baseline (215.013 us; speedup 1.0000x reference)
//
#include <hip/hip_runtime.h>

// Problem dims (fixed by reference setup_inputs)
#define BS   32
#define NF   64     // n_feat
#define NN   512    // N
#define JJ   4      // J
#define NOUT 128
#define CC   256    // J*NF
#define NC   8      // n-chunks in phase 1
#define ROWS 64     // NN/NC rows per chunk
#define MJC  2      // mj-chunks per row
#define ROW4 512    // float4 per (b,n) row  (NN*JJ/4)
#define CH4  256    // float4 per mj-chunk

// Phase 1: partial column-sums of W over n.
// W flat index = ((b*NN + n)*NN + m)*JJ + j  -> as float4: (b*NN + n)*ROW4 + m
// P4[(b*NC + nc)*ROW4 + m] = sum_{n in chunk nc} W4[(b*NN + n)*ROW4 + m]
__global__ __launch_bounds__(256) void sumW_kernel(const float4* __restrict__ W4,
                                                   float4* __restrict__ P4) {
    int blk  = blockIdx.x;          // b*NC*MJC + nc*MJC + mjc
    int mjc  = blk & (MJC - 1);
    int rest = blk >> 1;            // MJC == 2
    int nc   = rest & (NC - 1);
    int b    = rest >> 3;           // NC == 8
    int m    = mjc * CH4 + threadIdx.x;   // float4 index within row, [0, 512)

    const float4* p = W4 + ((size_t)(b * NN + nc * ROWS)) * ROW4 + m;
    float4 acc = make_float4(0.f, 0.f, 0.f, 0.f);
#pragma unroll 8
    for (int r = 0; r < ROWS; ++r) {
        float4 v = p[(size_t)r * ROW4];
        acc.x += v.x; acc.y += v.y; acc.z += v.z; acc.w += v.w;
    }
    P4[((size_t)(b * NC + nc)) * ROW4 + m] = acc;
}

// Phase 2: fold partials -> S, contract with X -> T, contract with fc_w -> y.
// One block per batch b.
__global__ __launch_bounds__(256) void finish_kernel(const float4* __restrict__ P4,
                                                     const float4* __restrict__ X4,
                                                     const float4* __restrict__ fcw4,
                                                     const float* __restrict__ fcb,
                                                     float* __restrict__ out) {
    // S stored [j][ms][m'] with m = ms*128 + m', padded to 132 to decorrelate
    // the 128-float stride from the 32-bank layout (ms*132 -> banks rotate by 4).
    __shared__ __align__(16) float S[JJ][4][132];
    __shared__ __align__(16) float Tp[4][CC];       // per-ms partial T, [ms][j*NF+f]
    __shared__ __align__(16) float4 Tsum4[CC / 4];  // final T as float4 over c

    int b = blockIdx.x;
    int t = threadIdx.x;

    // 1) S[b,m,j]: sum the NC partials. One float4 of P = S[m][j=0..3].
    for (int m = t; m < NN; m += 256) {
        float4 a = make_float4(0.f, 0.f, 0.f, 0.f);
#pragma unroll
        for (int nc = 0; nc < NC; ++nc) {
            float4 v = P4[((size_t)(b * NC + nc)) * ROW4 + m];
            a.x += v.x; a.y += v.y; a.z += v.z; a.w += v.w;
        }
        int ms = m >> 7, mr = m & 127;
        S[0][ms][mr] = a.x; S[1][ms][mr] = a.y; S[2][ms][mr] = a.z; S[3][ms][mr] = a.w;
    }
    __syncthreads();

    // 2) T[j][f] = sum_m S[j][m] * X[b,f,m], split over ms (4 m-ranges of 128).
    int f = t >> 2, ms = t & 3;
    const float4* xp = X4 + ((size_t)(b * NF + f)) * (NN / 4) + ms * 32;
    const float4* s0 = (const float4*)(&S[0][ms][0]);
    const float4* s1 = (const float4*)(&S[1][ms][0]);
    const float4* s2 = (const float4*)(&S[2][ms][0]);
    const float4* s3 = (const float4*)(&S[3][ms][0]);
    float t0 = 0.f, t1 = 0.f, t2 = 0.f, t3 = 0.f;
#pragma unroll 4
    for (int i = 0; i < 32; ++i) {
        float4 xv = xp[i];
        float4 a0 = s0[i], a1 = s1[i], a2 = s2[i], a3 = s3[i];
        t0 += xv.x * a0.x + xv.y * a0.y + xv.z * a0.z + xv.w * a0.w;
        t1 += xv.x * a1.x + xv.y * a1.y + xv.z * a1.z + xv.w * a1.w;
        t2 += xv.x * a2.x + xv.y * a2.y + xv.z * a2.z + xv.w * a2.w;
        t3 += xv.x * a3.x + xv.y * a3.y + xv.z * a3.z + xv.w * a3.w;
    }
    Tp[ms][0 * NF + f] = t0;
    Tp[ms][1 * NF + f] = t1;
    Tp[ms][2 * NF + f] = t2;
    Tp[ms][3 * NF + f] = t3;
    __syncthreads();

    // 3) Reduce ms partials: Tsum[c] = sum_ms Tp[ms][c]
    if (t < CC / 4) {
        const float4* r0 = (const float4*)Tp[0];
        const float4* r1 = (const float4*)Tp[1];
        const float4* r2 = (const float4*)Tp[2];
        const float4* r3 = (const float4*)Tp[3];
        float4 a = r0[t], b1 = r1[t], c = r2[t], d = r3[t];
        Tsum4[t] = make_float4(a.x + b1.x + c.x + d.x,
                               a.y + b1.y + c.y + d.y,
                               a.z + b1.z + c.z + d.z,
                               a.w + b1.w + c.w + d.w);
    }
    __syncthreads();

    // 4) y[b,o] = sum_c fc_w[o,c] * Tsum[c] + NN * fc_b[o]
    if (t < NOUT) {
        float acc = (float)NN * fcb[t];
#pragma unroll 8
        for (int i = 0; i < CC / 4; ++i) {
            float4 wv = fcw4[(size_t)t * (CC / 4) + i];
            float4 sv = Tsum4[i];
            acc += wv.x * sv.x + wv.y * sv.y + wv.z * sv.z + wv.w * sv.w;
        }
        out[b * NOUT + t] = acc;
    }
}

extern "C" void kernel_launch(void* const* d_in, const int* in_sizes, int n_in,
                              void* d_out, int out_size, void* d_ws, size_t ws_size,
                              hipStream_t stream) {
    // Inputs (setup_inputs order): X, W, fc_w, fc_b, N_batch, mask — all fp32.
    const float4* X4   = (const float4*)d_in[0];
    const float4* W4   = (const float4*)d_in[1];
    const float4* fcw4 = (const float4*)d_in[2];
    const float*  fcb  = (const float*)d_in[3];
    float* out = (float*)d_out;

    // Workspace: P partials, BS*NC*ROW4 float4 = 2 MiB. Fully overwritten by
    // sumW_kernel before finish_kernel reads it (0xAA poison is harmless).
    float4* P4 = (float4*)d_ws;

    sumW_kernel<<<BS * NC * MJC, 256, 0, stream>>>(W4, P4);
    finish_kernel<<<BS, 256, 0, stream>>>(P4, X4, fcw4, fcb, out);
}